// Round 8
// baseline (674.897 us; speedup 1.0000x reference)
//
#include <hip/hip_runtime.h>
#include <hip/hip_bf16.h>
#include <math.h>

#define Bz 64
#define Sz 512
#define Hz 768
#define Nz 128
#define Ez 1024
#define GHz 128
#define FHz 256
#define Lz 2
#define BNz (Bz * Nz)          // 8192

typedef short bf16x8 __attribute__((ext_vector_type(8)));
typedef float f32x4  __attribute__((ext_vector_type(4)));
typedef unsigned short ushort;

__device__ inline ushort f2b(float f) {          // f32 -> bf16 bits, round-to-nearest-even
    union { float f; unsigned u; } v; v.f = f;
    return (ushort)((v.u + 0x7FFFu + ((v.u >> 16) & 1u)) >> 16);
}
__device__ inline float b2f(ushort u) {
    union { unsigned u; float f; } v; v.u = ((unsigned)u) << 16;
    return v.f;
}

// ============ node gather: per (b,n) block; wave-synchronous gate; writes nf in bf16 ============
__global__ void k_node_gather(const float* __restrict__ lh, const int* __restrict__ submap,
                              const float* __restrict__ wr, const float* __restrict__ br,
                              ushort* __restrict__ nfb) {
    int n = blockIdx.x, b = blockIdx.y;
    int t = threadIdx.x;                  // 128 = 2 waves
    int lane = t & 63, wid = t >> 6;
    __shared__ int list[Sz];
    __shared__ int lcnt;
    __shared__ float partial[Hz];
    if (t == 0) lcnt = 0;
    __syncthreads();
    #pragma unroll
    for (int j = 0; j < 4; ++j) {
        int s = t + 128 * j;
        if (submap[b * Sz + s] == n) { int p = atomicAdd(&lcnt, 1); list[p] = s; }
    }
    __syncthreads();
    int cnt = lcnt;
    float brv = br[0];
    const float* wp = wr + lane * 12;
    float4 w0 = *(const float4*)&wp[0];
    float4 w1 = *(const float4*)&wp[4];
    float4 w2 = *(const float4*)&wp[8];
    float4 a0 = {0,0,0,0}, a1 = {0,0,0,0}, a2 = {0,0,0,0};
    for (int i = wid; i < cnt; i += 2) {
        const float* x = lh + (size_t)(b * Sz + list[i]) * Hz + lane * 12;
        float4 v0 = *(const float4*)&x[0];
        float4 v1 = *(const float4*)&x[4];
        float4 v2 = *(const float4*)&x[8];
        float p = v0.x*w0.x + v0.y*w0.y + v0.z*w0.z + v0.w*w0.w
                + v1.x*w1.x + v1.y*w1.y + v1.z*w1.z + v1.w*w1.w
                + v2.x*w2.x + v2.y*w2.y + v2.z*w2.z + v2.w*w2.w;
        #pragma unroll
        for (int off = 32; off > 0; off >>= 1) p += __shfl_down(p, off);
        float z = __shfl(p, 0) + brv;
        float g = 1.0f / (1.0f + __expf(-z));
        a0.x += g*v0.x; a0.y += g*v0.y; a0.z += g*v0.z; a0.w += g*v0.w;
        a1.x += g*v1.x; a1.y += g*v1.y; a1.z += g*v1.z; a1.w += g*v1.w;
        a2.x += g*v2.x; a2.y += g*v2.y; a2.z += g*v2.z; a2.w += g*v2.w;
    }
    if (wid == 1) {
        float* pp = partial + lane * 12;
        *(float4*)&pp[0] = a0; *(float4*)&pp[4] = a1; *(float4*)&pp[8] = a2;
    }
    __syncthreads();
    if (wid == 0) {
        float invc = 1.0f / fmaxf((float)cnt, 1.0f);
        const float* pp = partial + lane * 12;
        float4 p0 = *(const float4*)&pp[0];
        float4 p1 = *(const float4*)&pp[4];
        float4 p2 = *(const float4*)&pp[8];
        float o[12];
        o[0]=(a0.x+p0.x)*invc; o[1]=(a0.y+p0.y)*invc; o[2]=(a0.z+p0.z)*invc; o[3]=(a0.w+p0.w)*invc;
        o[4]=(a1.x+p1.x)*invc; o[5]=(a1.y+p1.y)*invc; o[6]=(a1.z+p1.z)*invc; o[7]=(a1.w+p1.w)*invc;
        o[8]=(a2.x+p2.x)*invc; o[9]=(a2.y+p2.y)*invc; o[10]=(a2.z+p2.z)*invc; o[11]=(a2.w+p2.w)*invc;
        unsigned* ob = (unsigned*)(nfb + (size_t)(b * Nz + n) * Hz + lane * 12);
        #pragma unroll
        for (int j = 0; j < 6; ++j)
            ob[j] = (unsigned)f2b(o[2*j]) | ((unsigned)f2b(o[2*j+1]) << 16);
    }
}

// ============ MFMA gemm phase (device): acc += A_bf16(128 x K) @ W_f32(K x 128) ============
// Verified R6 structure; W converted f32->bf16 during register-prefetch staging.
#define GSP 72                 // LDS row stride in bf16 (144 B, 16B-aligned)
template <int K>
__device__ inline void gemm_phase(const ushort* __restrict__ Ab, const float* __restrict__ W,
                                  ushort* As, ushort* Bt, f32x4 (&acc)[2][8], int tid) {
    int w = tid >> 6, lane = tid & 63;
    int q = lane >> 4, l16 = lane & 15;
    int ar[4], aseg[4], bn[4], bks[4];
    #pragma unroll
    for (int rep = 0; rep < 4; ++rep) {
        int idx = tid + 256 * rep;
        ar[rep] = idx >> 3;  aseg[rep] = idx & 7;    // A: 128 rows x 8 segs of 8 k
        bn[rep] = idx & 127; bks[rep] = idx >> 7;    // B: 128 n x 8 ksegs of 8 k
    }
    uint4 apre[4], bpre[4];
    auto loadT = [&](int k0) {
        #pragma unroll
        for (int rep = 0; rep < 4; ++rep)
            apre[rep] = *(const uint4*)&Ab[(size_t)ar[rep] * K + k0 + aseg[rep] * 8];
        #pragma unroll
        for (int rep = 0; rep < 4; ++rep) {
            ushort u[8];
            #pragma unroll
            for (int j = 0; j < 8; ++j)
                u[j] = f2b(W[(size_t)(k0 + bks[rep] * 8 + j) * 128 + bn[rep]]);
            bpre[rep].x = (unsigned)u[0] | ((unsigned)u[1] << 16);
            bpre[rep].y = (unsigned)u[2] | ((unsigned)u[3] << 16);
            bpre[rep].z = (unsigned)u[4] | ((unsigned)u[5] << 16);
            bpre[rep].w = (unsigned)u[6] | ((unsigned)u[7] << 16);
        }
    };
    loadT(0);
    for (int kk = 0; kk < K; kk += 64) {
        __syncthreads();                  // prior users of this LDS region done
        #pragma unroll
        for (int rep = 0; rep < 4; ++rep) {
            *(uint4*)&As[ar[rep] * GSP + aseg[rep] * 8] = apre[rep];
            *(uint4*)&Bt[bn[rep] * GSP + bks[rep] * 8] = bpre[rep];
        }
        if (kk + 64 < K) loadT(kk + 64);  // next tile's global loads in flight
        __syncthreads();
        #pragma unroll
        for (int ks = 0; ks < 64; ks += 32) {
            bf16x8 af0 = *(const bf16x8*)&As[(w * 32 + l16) * GSP + ks + q * 8];
            bf16x8 af1 = *(const bf16x8*)&As[(w * 32 + 16 + l16) * GSP + ks + q * 8];
            #pragma unroll
            for (int ct = 0; ct < 8; ++ct) {
                bf16x8 bv = *(const bf16x8*)&Bt[(ct * 16 + l16) * GSP + ks + q * 8];
                acc[0][ct] = __builtin_amdgcn_mfma_f32_16x16x32_bf16(af0, bv, acc[0][ct], 0, 0, 0);
                acc[1][ct] = __builtin_amdgcn_mfma_f32_16x16x32_bf16(af1, bv, acc[1][ct], 0, 0, 0);
            }
        }
    }
}

// ============ k_batch: gemm1 -> edge1 -> gemm2 -> edge2+pool -> MLP head, one block per b ============
__global__ __launch_bounds__(256) void k_batch(
    const ushort* __restrict__ nfb, const int* __restrict__ ei,
    const float* __restrict__ W1, const float* __restrict__ b1,
    const float* __restrict__ W2, const float* __restrict__ b2,
    const float* __restrict__ lh,
    const float* __restrict__ Wf1, const float* __restrict__ bf1,
    const float* __restrict__ Wf2, const float* __restrict__ bf2,
    ushort* __restrict__ x1b, float* __restrict__ out) {
    // LDS: regionA[49152] | srcl[4096] | dstl[4096] | hist[512] | sdinv[512] | pooled[512]
    __shared__ __align__(16) char lds[49152 + 8192 + 1536];
    ushort* As    = (ushort*)lds;                 // gemm: 18432 B
    ushort* Bt    = (ushort*)(lds + 18432);       // gemm: 18432 B
    ushort* htile = (ushort*)lds;                 // edge: 128x64 bf16 = 16384 B
    float*  xout  = (float*)(lds + 16384);        // edge: 128x64 f32  = 32768 B
    float*  inbuf = (float*)lds;                  // mlp: 896 f32 = 3584 B
    float*  wred  = (float*)(lds + 4096);         // mlp: 8 f32
    int*    srcl  = (int*)(lds + 49152);
    int*    dstl  = (int*)(lds + 53248);
    int*    hist  = (int*)(lds + 57344);
    float*  sdinv = (float*)(lds + 57856);
    float*  pooled= (float*)(lds + 58368);

    int b = blockIdx.x;
    int tid = threadIdx.x;                // 256

    // ---- edge lists + degree hist + dinv + pooled init (once; reused both layers) ----
    if (tid < Nz) { hist[tid] = 0; pooled[tid] = 0.0f; }
    __syncthreads();
    #pragma unroll
    for (int j = 0; j < 4; ++j) {
        int e = tid + 256 * j;
        int s = ei[b * 2 * Ez + e], d = ei[b * 2 * Ez + Ez + e];
        srcl[e] = s; dstl[e] = d;
        atomicAdd(&hist[d], 1);
    }
    __syncthreads();
    if (tid < Nz) sdinv[tid] = rsqrtf((float)hist[tid] + 1.0f);
    // (edge_phase barriers cover sdinv visibility)

    f32x4 acc[2][8];
    #pragma unroll
    for (int rt = 0; rt < 2; ++rt)
        #pragma unroll
        for (int ct = 0; ct < 8; ++ct) acc[rt][ct] = (f32x4){0, 0, 0, 0};

    int w = tid >> 6, lane = tid & 63;
    int q = lane >> 4, l16 = lane & 15;

    // edge phase: acc (C of gemm) -> LDS scatter -> relu(+bias); layer1 writes x1b, layer2 pools
    auto edge_phase = [&](bool layer2, const float* __restrict__ bias) {
        for (int half = 0; half < 2; ++half) {
            __syncthreads();              // prior users of regionA done
            #pragma unroll
            for (int rt = 0; rt < 2; ++rt)
                #pragma unroll
                for (int ctl = 0; ctl < 4; ++ctl) {
                    int ct = half * 4 + ctl;
                    #pragma unroll
                    for (int r = 0; r < 4; ++r)
                        htile[(w * 32 + rt * 16 + q * 4 + r) * 64 + ctl * 16 + l16] =
                            f2b(acc[rt][ct][r]);
                }
            __syncthreads();
            for (int i = tid; i < Nz * 64; i += 256) {     // self loop init
                int row = i >> 6;
                xout[i] = b2f(htile[i]) * sdinv[row] * sdinv[row];
            }
            __syncthreads();
            int c = tid & 63;
            for (int e0 = 0; e0 < Ez; e0 += 4) {           // 4 edges/iter, 64 cols each
                int et = e0 + (tid >> 6);
                int s = srcl[et], d = dstl[et];
                float nm = sdinv[s] * sdinv[d];
                atomicAdd(&xout[d * 64 + c], b2f(htile[s * 64 + c]) * nm);
            }
            __syncthreads();
            if (!layer2) {
                for (int i = tid; i < Nz * 64; i += 256) {
                    int row = i >> 6, cc = i & 63;
                    float v = fmaxf(xout[i] + bias[half * 64 + cc], 0.0f);
                    x1b[((size_t)(b * Nz + row)) * GHz + half * 64 + cc] = f2b(v);
                }
            } else {
                for (int i = tid; i < Nz * 64; i += 256) {
                    int row = i >> 6, cc = i & 63;
                    float v = fmaxf(xout[i] + bias[half * 64 + cc], 0.0f);
                    atomicAdd(&pooled[half * 64 + cc], v);
                }
            }
        }
    };

    // ---- GCN layer 1 ----
    gemm_phase<Hz>(nfb + (size_t)b * Nz * Hz, W1, As, Bt, acc, tid);
    edge_phase(false, b1);
    __threadfence_block();                // x1b writes visible to this block (same CU)
    __syncthreads();

    // ---- GCN layer 2 ----
    #pragma unroll
    for (int rt = 0; rt < 2; ++rt)
        #pragma unroll
        for (int ct = 0; ct < 8; ++ct) acc[rt][ct] = (f32x4){0, 0, 0, 0};
    gemm_phase<GHz>(x1b + (size_t)b * Nz * GHz, W2, As, Bt, acc, tid);
    edge_phase(true, b2);

    // ---- MLP head ----
    __syncthreads();                      // regionA free; pooled final
    for (int i = tid; i < Hz; i += 256) inbuf[i] = lh[(size_t)b * Sz * Hz + i];  // cls row
    if (tid < Nz) inbuf[Hz + tid] = pooled[tid] * (1.0f / Nz);
    __syncthreads();
    float a0 = 0.0f;                      // col = tid (0..255)
    #pragma unroll 4
    for (int k = 0; k < Hz + GHz; ++k) a0 += inbuf[k] * Wf1[(size_t)k * FHz + tid];
    float hval = fmaxf(a0 + bf1[tid], 0.0f);
    #pragma unroll
    for (int l = 0; l < Lz; ++l) {
        float v = hval * Wf2[tid * Lz + l];
        #pragma unroll
        for (int off = 32; off > 0; off >>= 1) v += __shfl_down(v, off);
        if ((tid & 63) == 0) wred[(tid >> 6) * 2 + l] = v;
    }
    __syncthreads();
    if (tid == 0) {
        out[b * Lz + 0] = wred[0] + wred[2] + wred[4] + wred[6] + bf2[0];
        out[b * Lz + 1] = wred[1] + wred[3] + wred[5] + wred[7] + bf2[1];
    }
}

extern "C" void kernel_launch(void* const* d_in, const int* in_sizes, int n_in,
                              void* d_out, int out_size, void* d_ws, size_t ws_size,
                              hipStream_t stream) {
    const float* lh     = (const float*)d_in[0];
    const int*   submap = (const int*)d_in[1];
    const int*   ei     = (const int*)d_in[2];
    const float* wr  = (const float*)d_in[4];
    const float* br  = (const float*)d_in[5];
    const float* W1  = (const float*)d_in[6];
    const float* b1  = (const float*)d_in[7];
    const float* W2  = (const float*)d_in[8];
    const float* b2  = (const float*)d_in[9];
    const float* Wf1 = (const float*)d_in[10];
    const float* bf1 = (const float*)d_in[11];
    const float* Wf2 = (const float*)d_in[12];
    const float* bf2 = (const float*)d_in[13];
    float* out = (float*)d_out;

    // ---- workspace ----
    char* p = (char*)d_ws;
    ushort* nfb = (ushort*)p;  p += (size_t)BNz * Hz * 2;      // 12.6 MB bf16
    ushort* x1b = (ushort*)p;  p += (size_t)BNz * GHz * 2;     // 2 MB bf16

    // 2 dispatches total; no memsets, no global atomics
    k_node_gather<<<dim3(Nz, Bz), 128, 0, stream>>>(lh, submap, wr, br, nfb);
    k_batch<<<Bz, 256, 0, stream>>>(nfb, ei, W1, b1, W2, b2, lh, Wf1, bf1, Wf2, bf2, x1b, out);
}

// Round 9
// 261.586 us; speedup vs baseline: 2.5800x; 2.5800x over previous
//
#include <hip/hip_runtime.h>
#include <hip/hip_bf16.h>
#include <math.h>

#define Bz 64
#define Sz 512
#define Hz 768
#define Nz 128
#define Ez 1024
#define GHz 128
#define FHz 256
#define Lz 2
#define BNz (Bz * Nz)          // 8192

typedef short bf16x8 __attribute__((ext_vector_type(8)));
typedef float f32x4  __attribute__((ext_vector_type(4)));
typedef unsigned short ushort;

__device__ inline ushort f2b(float f) {          // f32 -> bf16 bits, round-to-nearest-even
    union { float f; unsigned u; } v; v.f = f;
    return (ushort)((v.u + 0x7FFFu + ((v.u >> 16) & 1u)) >> 16);
}

// ============ prep: convert W1,W2 to bf16 (blocks 0..447) + per-batch CSR build (blocks 448..511) ============
// CSR: edges sorted by dst; srcsG/wnG hold src index and dinv[s]*dinv[d] per edge; rowptrG[b*129+n].
__global__ void k_prep(const float* __restrict__ W1, const float* __restrict__ W2,
                       const int* __restrict__ ei,
                       ushort* __restrict__ W1b, ushort* __restrict__ W2b,
                       int* __restrict__ rowptrG, int* __restrict__ srcsG,
                       float* __restrict__ wnG, float* __restrict__ dinvG) {
    int blk = blockIdx.x, t = threadIdx.x;       // 256 threads
    if (blk < 448) {                             // weight conversion
        int i = blk * 256 + t;
        if (i < Hz * GHz) W1b[i] = f2b(W1[i]);
        int j = i - Hz * GHz;
        if (j >= 0 && j < GHz * GHz) W2b[j] = f2b(W2[j]);
        return;
    }
    int b = blk - 448;
    __shared__ int srcl[Ez], dstl[Ez];
    __shared__ int hist[Nz], off[Nz], rp[Nz + 1];
    __shared__ float di[Nz];
    if (t < Nz) { hist[t] = 0; off[t] = 0; }
    __syncthreads();
    #pragma unroll
    for (int j = 0; j < 4; ++j) {
        int e = t + 256 * j;
        int s = ei[b * 2 * Ez + e], d = ei[b * 2 * Ez + Ez + e];
        srcl[e] = s; dstl[e] = d;
        atomicAdd(&hist[d], 1);
    }
    __syncthreads();
    if (t < Nz) {
        di[t] = rsqrtf((float)hist[t] + 1.0f);
        dinvG[b * Nz + t] = di[t];
    }
    __syncthreads();
    if (t == 0) {
        int run = 0;
        for (int n = 0; n < Nz; ++n) { rp[n] = run; run += hist[n]; }
        rp[Nz] = run;
    }
    __syncthreads();
    #pragma unroll
    for (int j = 0; j < 4; ++j) {
        int e = t + 256 * j;
        int s = srcl[e], d = dstl[e];
        int pos = rp[d] + atomicAdd(&off[d], 1);
        srcsG[b * Ez + pos] = s;
        wnG[b * Ez + pos] = di[s] * di[d];
    }
    if (t < Nz + 1) rowptrG[b * (Nz + 1) + t] = rp[t];
}

// ============ node gather: per (b,n) block; wave-synchronous gate; writes nf in bf16 ============
__global__ void k_node_gather(const float* __restrict__ lh, const int* __restrict__ submap,
                              const float* __restrict__ wr, const float* __restrict__ br,
                              ushort* __restrict__ nfb) {
    int n = blockIdx.x, b = blockIdx.y;
    int t = threadIdx.x;                  // 128 = 2 waves
    int lane = t & 63, wid = t >> 6;
    __shared__ int list[Sz];
    __shared__ int lcnt;
    __shared__ float partial[Hz];
    if (t == 0) lcnt = 0;
    __syncthreads();
    #pragma unroll
    for (int j = 0; j < 4; ++j) {
        int s = t + 128 * j;
        if (submap[b * Sz + s] == n) { int p = atomicAdd(&lcnt, 1); list[p] = s; }
    }
    __syncthreads();
    int cnt = lcnt;
    float brv = br[0];
    const float* wp = wr + lane * 12;
    float4 w0 = *(const float4*)&wp[0];
    float4 w1 = *(const float4*)&wp[4];
    float4 w2 = *(const float4*)&wp[8];
    float4 a0 = {0,0,0,0}, a1 = {0,0,0,0}, a2 = {0,0,0,0};
    for (int i = wid; i < cnt; i += 2) {
        const float* x = lh + (size_t)(b * Sz + list[i]) * Hz + lane * 12;
        float4 v0 = *(const float4*)&x[0];
        float4 v1 = *(const float4*)&x[4];
        float4 v2 = *(const float4*)&x[8];
        float p = v0.x*w0.x + v0.y*w0.y + v0.z*w0.z + v0.w*w0.w
                + v1.x*w1.x + v1.y*w1.y + v1.z*w1.z + v1.w*w1.w
                + v2.x*w2.x + v2.y*w2.y + v2.z*w2.z + v2.w*w2.w;
        #pragma unroll
        for (int off = 32; off > 0; off >>= 1) p += __shfl_down(p, off);
        float z = __shfl(p, 0) + brv;
        float g = 1.0f / (1.0f + __expf(-z));
        a0.x += g*v0.x; a0.y += g*v0.y; a0.z += g*v0.z; a0.w += g*v0.w;
        a1.x += g*v1.x; a1.y += g*v1.y; a1.z += g*v1.z; a1.w += g*v1.w;
        a2.x += g*v2.x; a2.y += g*v2.y; a2.z += g*v2.z; a2.w += g*v2.w;
    }
    if (wid == 1) {
        float* pp = partial + lane * 12;
        *(float4*)&pp[0] = a0; *(float4*)&pp[4] = a1; *(float4*)&pp[8] = a2;
    }
    __syncthreads();
    if (wid == 0) {
        float invc = 1.0f / fmaxf((float)cnt, 1.0f);
        const float* pp = partial + lane * 12;
        float4 p0 = *(const float4*)&pp[0];
        float4 p1 = *(const float4*)&pp[4];
        float4 p2 = *(const float4*)&pp[8];
        float o[12];
        o[0]=(a0.x+p0.x)*invc; o[1]=(a0.y+p0.y)*invc; o[2]=(a0.z+p0.z)*invc; o[3]=(a0.w+p0.w)*invc;
        o[4]=(a1.x+p1.x)*invc; o[5]=(a1.y+p1.y)*invc; o[6]=(a1.z+p1.z)*invc; o[7]=(a1.w+p1.w)*invc;
        o[8]=(a2.x+p2.x)*invc; o[9]=(a2.y+p2.y)*invc; o[10]=(a2.z+p2.z)*invc; o[11]=(a2.w+p2.w)*invc;
        unsigned* ob = (unsigned*)(nfb + (size_t)(b * Nz + n) * Hz + lane * 12);
        #pragma unroll
        for (int j = 0; j < 6; ++j)
            ob[j] = (unsigned)f2b(o[2*j]) | ((unsigned)f2b(o[2*j+1]) << 16);
    }
}

// ============ MFMA GEMM: C(BN x 128) = A_bf16(BN x K) @ W_bf16(K x 128), f32 out ============
// 64x128 tile (grid 128 -- R8 lesson: avoid grid starvation), BK=64, register prefetch.
// Layouts (m89/m91-verified): A-frag A[m=lane&15][k=q*8+j]; B-frag B[k=q*8+j][n=lane&15];
// C/D: row=q*4+reg, col=lane&15.
#define GSP 72                 // LDS row stride in bf16 (144 B, 16B-aligned)
template <int K>
__global__ void k_gemm_mfma(const ushort* __restrict__ A, const ushort* __restrict__ W,
                            float* __restrict__ C) {
    __shared__ __align__(16) ushort As[64 * GSP];    // [row][k]  (64-k slice)
    __shared__ __align__(16) ushort Bt[128 * GSP];   // [n][k]
    int row_base = blockIdx.x * 64;
    int tid = threadIdx.x;                // 256 = 4 waves; wave w: rows [w*16, w*16+16)
    int w = tid >> 6, lane = tid & 63;
    int q = lane >> 4, l16 = lane & 15;
    f32x4 acc[8];
    #pragma unroll
    for (int ct = 0; ct < 8; ++ct) acc[ct] = (f32x4){0, 0, 0, 0};

    int ar[2], aseg[2], bn[4], bks[4];
    #pragma unroll
    for (int rep = 0; rep < 2; ++rep) {
        int idx = tid + 256 * rep;                   // A: 64 rows x 8 segs of 8 k
        ar[rep] = idx >> 3; aseg[rep] = idx & 7;
    }
    #pragma unroll
    for (int rep = 0; rep < 4; ++rep) {
        int idx = tid + 256 * rep;                   // B: 128 n x 8 ksegs of 8 k
        bn[rep] = idx & 127; bks[rep] = idx >> 7;
    }
    uint4 apre[2], bpre[4];
    auto loadT = [&](int k0) {
        #pragma unroll
        for (int rep = 0; rep < 2; ++rep)
            apre[rep] = *(const uint4*)&A[(size_t)(row_base + ar[rep]) * K + k0 + aseg[rep] * 8];
        #pragma unroll
        for (int rep = 0; rep < 4; ++rep) {
            ushort u[8];
            #pragma unroll
            for (int j = 0; j < 8; ++j)
                u[j] = W[(size_t)(k0 + bks[rep] * 8 + j) * 128 + bn[rep]];
            bpre[rep].x = (unsigned)u[0] | ((unsigned)u[1] << 16);
            bpre[rep].y = (unsigned)u[2] | ((unsigned)u[3] << 16);
            bpre[rep].z = (unsigned)u[4] | ((unsigned)u[5] << 16);
            bpre[rep].w = (unsigned)u[6] | ((unsigned)u[7] << 16);
        }
    };
    loadT(0);
    for (int kk = 0; kk < K; kk += 64) {
        __syncthreads();
        #pragma unroll
        for (int rep = 0; rep < 2; ++rep)
            *(uint4*)&As[ar[rep] * GSP + aseg[rep] * 8] = apre[rep];
        #pragma unroll
        for (int rep = 0; rep < 4; ++rep)
            *(uint4*)&Bt[bn[rep] * GSP + bks[rep] * 8] = bpre[rep];
        if (kk + 64 < K) loadT(kk + 64);  // next tile's global loads in flight during MFMAs
        __syncthreads();
        #pragma unroll
        for (int ks = 0; ks < 64; ks += 32) {
            bf16x8 af = *(const bf16x8*)&As[(w * 16 + l16) * GSP + ks + q * 8];
            #pragma unroll
            for (int ct = 0; ct < 8; ++ct) {
                bf16x8 bv = *(const bf16x8*)&Bt[(ct * 16 + l16) * GSP + ks + q * 8];
                acc[ct] = __builtin_amdgcn_mfma_f32_16x16x32_bf16(af, bv, acc[ct], 0, 0, 0);
            }
        }
    }
    #pragma unroll
    for (int ct = 0; ct < 8; ++ct)
        #pragma unroll
        for (int r = 0; r < 4; ++r)
            C[(size_t)(row_base + w * 16 + q * 4 + r) * 128 + ct * 16 + l16] = acc[ct][r];
}

// ============ edge apply via CSR: out[d] = relu(self + sum_csr h[s]*wn + bias) ============
template <bool OUT_BF>
__global__ void k_edge_apply(const float* __restrict__ h, const int* __restrict__ rowptrG,
                             const int* __restrict__ srcsG, const float* __restrict__ wnG,
                             const float* __restrict__ dinvG, const float* __restrict__ bias,
                             float* __restrict__ outf, ushort* __restrict__ outb) {
    int d = blockIdx.x, b = blockIdx.y;
    int t = threadIdx.x;                  // 128 = col
    int p0 = rowptrG[b * (Nz + 1) + d], p1 = rowptrG[b * (Nz + 1) + d + 1];
    float dd = dinvG[b * Nz + d];
    float acc = h[(size_t)(b * Nz + d) * GHz + t] * dd * dd;      // self loop
    for (int i = p0; i < p1; ++i) {
        int s = srcsG[b * Ez + i];                                 // wave-uniform broadcast
        float nm = wnG[b * Ez + i];
        acc += h[(size_t)(b * Nz + s) * GHz + t] * nm;
    }
    float v = fmaxf(acc + bias[t], 0.0f);
    if (OUT_BF) outb[(size_t)(b * Nz + d) * GHz + t] = f2b(v);
    else        outf[(size_t)(b * Nz + d) * GHz + t] = v;
}

// ============ fused head: pooled = mean(x2[b]); h = relu([cls,pooled]@Wf1+bf1); out = h@Wf2+bf2 ============
__global__ void k_head(const float* __restrict__ lh, const float* __restrict__ x2,
                       const float* __restrict__ Wf1, const float* __restrict__ bf1,
                       const float* __restrict__ Wf2, const float* __restrict__ bf2,
                       float* __restrict__ out) {
    int b = blockIdx.x;
    int t = threadIdx.x;                  // 256
    __shared__ float in[Hz + GHz];        // 896
    __shared__ float buf[2][128];
    __shared__ float4 red4[4][64];
    __shared__ float hvec[FHz];
    __shared__ float red[256];
    for (int i = t; i < Hz; i += 256) in[i] = lh[(size_t)b * Sz * Hz + i];   // cls = s=0 row
    int col = t & 127, half = t >> 7;
    float s = 0.0f;
    for (int r = 0; r < 64; ++r)
        s += x2[(size_t)(b * Nz + half * 64 + r) * GHz + col];
    buf[half][col] = s;
    __syncthreads();
    if (t < 128) in[Hz + t] = (buf[0][t] + buf[1][t]) * (1.0f / Nz);
    __syncthreads();
    int c4 = t & 63, kc = t >> 6;
    float4 a = {0, 0, 0, 0};
    int k1 = kc * 224 + 224;
    for (int k = kc * 224; k < k1; ++k) {
        float iv = in[k];
        float4 w = *(const float4*)&Wf1[(size_t)k * FHz + c4 * 4];
        a.x += iv * w.x; a.y += iv * w.y; a.z += iv * w.z; a.w += iv * w.w;
    }
    red4[kc][c4] = a;
    __syncthreads();
    if (t < 64) {
        float4 s0 = red4[0][t], s1 = red4[1][t], s2 = red4[2][t], s3 = red4[3][t];
        float4 bb = *(const float4*)&bf1[t * 4];
        hvec[t * 4 + 0] = fmaxf(s0.x + s1.x + s2.x + s3.x + bb.x, 0.0f);
        hvec[t * 4 + 1] = fmaxf(s0.y + s1.y + s2.y + s3.y + bb.y, 0.0f);
        hvec[t * 4 + 2] = fmaxf(s0.z + s1.z + s2.z + s3.z + bb.z, 0.0f);
        hvec[t * 4 + 3] = fmaxf(s0.w + s1.w + s2.w + s3.w + bb.w, 0.0f);
    }
    __syncthreads();
    float hv = hvec[t];
    for (int l = 0; l < Lz; ++l) {
        red[t] = hv * Wf2[t * Lz + l];
        __syncthreads();
        for (int s2 = 128; s2 > 0; s2 >>= 1) {
            if (t < s2) red[t] += red[t + s2];
            __syncthreads();
        }
        if (t == 0) out[b * Lz + l] = red[0] + bf2[l];
        __syncthreads();
    }
}

extern "C" void kernel_launch(void* const* d_in, const int* in_sizes, int n_in,
                              void* d_out, int out_size, void* d_ws, size_t ws_size,
                              hipStream_t stream) {
    const float* lh     = (const float*)d_in[0];
    const int*   submap = (const int*)d_in[1];
    const int*   ei     = (const int*)d_in[2];
    const float* wr  = (const float*)d_in[4];
    const float* br  = (const float*)d_in[5];
    const float* W1  = (const float*)d_in[6];
    const float* b1  = (const float*)d_in[7];
    const float* W2  = (const float*)d_in[8];
    const float* b2  = (const float*)d_in[9];
    const float* Wf1 = (const float*)d_in[10];
    const float* bf1 = (const float*)d_in[11];
    const float* Wf2 = (const float*)d_in[12];
    const float* bf2 = (const float*)d_in[13];
    float* out = (float*)d_out;

    // ---- workspace layout (16B-aligned chunks) ----
    char* p = (char*)d_ws;
    ushort* nfb  = (ushort*)p;  p += (size_t)BNz * Hz * 2;      // 12.6 MB bf16
    ushort* W1b  = (ushort*)p;  p += (size_t)Hz * GHz * 2;
    ushort* W2b  = (ushort*)p;  p += (size_t)GHz * GHz * 2;
    float*  h1   = (float*)p;   p += (size_t)BNz * GHz * 4;
    ushort* x1b  = (ushort*)p;  p += (size_t)BNz * GHz * 2;
    float*  h2   = (float*)p;   p += (size_t)BNz * GHz * 4;
    float*  x2   = (float*)p;   p += (size_t)BNz * GHz * 4;
    int*    rowptrG = (int*)p;  p += (size_t)Bz * (Nz + 1) * 4;
    int*    srcsG   = (int*)p;  p += (size_t)Bz * Ez * 4;
    float*  wnG     = (float*)p; p += (size_t)Bz * Ez * 4;
    float*  dinvG   = (float*)p; p += (size_t)Bz * Nz * 4;

    // 7 dispatches; no memsets, no global atomics
    k_prep<<<512, 256, 0, stream>>>(W1, W2, ei, W1b, W2b, rowptrG, srcsG, wnG, dinvG);
    k_node_gather<<<dim3(Nz, Bz), 128, 0, stream>>>(lh, submap, wr, br, nfb);

    k_gemm_mfma<Hz><<<BNz / 64, 256, 0, stream>>>(nfb, W1b, h1);
    k_edge_apply<true><<<dim3(Nz, Bz), 128, 0, stream>>>(h1, rowptrG, srcsG, wnG, dinvG, b1, nullptr, x1b);

    k_gemm_mfma<GHz><<<BNz / 64, 256, 0, stream>>>(x1b, W2b, h2);
    k_edge_apply<false><<<dim3(Nz, Bz), 128, 0, stream>>>(h2, rowptrG, srcsG, wnG, dinvG, b2, x2, nullptr);

    k_head<<<Bz, 256, 0, stream>>>(lh, x2, Wf1, bf1, Wf2, bf2, out);
}